// Round 1
// baseline (1023.159 us; speedup 1.0000x reference)
//
#include <hip/hip_runtime.h>
#include <cstddef>

#define B_      4
#define D_      128
#define H_      512
#define W_      512
#define NCELL_  900     // 30*30 cells per batch
#define NS_     3600    // B_*NCELL_
#define NK_     13
#define SC_     3601    // score row length
#define TILE_   64
#define KC_     32

// _OFFS: pairs (i,j), i*i+j*j<=4, i-major order. OFFS[0]=i (added to x), OFFS[1]=j (added to y)
__constant__ int c_OI[NK_] = {-2,-1,-1,-1, 0, 0,0,0,0, 1,1,1, 2};
__constant__ int c_OJ[NK_] = { 0,-1, 0, 1,-2,-1,0,1,2,-1,0,1, 0};

// ---------------- cell argmax sampling (det1: cells 0..3599, det2: 3600..7199) --------------
__global__ __launch_bounds__(256) void sample_kernel(const float* __restrict__ det1,
                                                     const float* __restrict__ det2,
                                                     int* __restrict__ pos_row,
                                                     int* __restrict__ pos_col) {
    int cell = blockIdx.x;
    const float* det = det1;
    int c = cell;
    if (cell >= NS_) { det = det2; c = cell - NS_; }
    int b  = c / NCELL_;
    int rc = (c % NCELL_) / 30;
    int cc = c % 30;
    int t = threadIdx.x;              // t = i*16 + j, flat argmax order
    int i = t >> 4, j = t & 15;
    int y = 16 + rc * 16 + i;
    int x = 16 + cc * 16 + j;
    float v = det[(b * H_ + y) * W_ + x];

    __shared__ float sv[256];
    __shared__ int   si[256];
    sv[t] = v; si[t] = t;
    __syncthreads();
    for (int s = 128; s > 0; s >>= 1) {
        if (t < s) {
            float v2 = sv[t + s]; int i2 = si[t + s];
            // first-occurrence semantics: strictly greater wins; ties keep lower index
            if (v2 > sv[t] || (v2 == sv[t] && i2 < si[t])) { sv[t] = v2; si[t] = i2; }
        }
        __syncthreads();
    }
    if (t == 0) {
        int best = si[0];
        pos_row[cell] = 16 + rc * 16 + (best >> 4);
        pos_col[cell] = 16 + cc * 16 + (best & 15);
    }
}

// ---------------- per-sample prep for det1 samples --------------------------------------
// NOTE reference index swap: H-index = pos_col, W-index = pos_row (y1=cols, x1=rows).
__global__ __launch_bounds__(64) void prep1_kernel(const float* __restrict__ des1,
                                                   const float* __restrict__ des2,
                                                   const float* __restrict__ qlt1,
                                                   const float* __restrict__ qlt2,
                                                   const float* __restrict__ aflow,
                                                   const int* __restrict__ pos_row,
                                                   const int* __restrict__ pos_col,
                                                   int* __restrict__ xy2x_out,
                                                   int* __restrict__ xy2y_out,
                                                   float* __restrict__ Amat,
                                                   float* __restrict__ out_scores,
                                                   float* __restrict__ out_mask,
                                                   float* __restrict__ out_qlt) {
    int n = blockIdx.x;
    int lane = threadIdx.x;           // 64 lanes, each owns d and d+64
    int b = n / NCELL_;
    int row = pos_row[n], col = pos_col[n];
    int d0 = lane;

    const float* p1 = des1 + ((b * D_ + d0) * H_ + col) * W_ + row;
    float a0 = p1[0];
    float a1 = p1[64 * H_ * W_];
    Amat[n * D_ + d0]      = a0;
    Amat[n * D_ + d0 + 64] = a1;

    float fx = aflow[((b * 2 + 0) * H_ + col) * W_ + row];
    float fy = aflow[((b * 2 + 1) * H_ + col) * W_ + row];
    int xx = (int)(fx + 0.5f);        // trunc toward zero, matches astype(int32)
    int yy = (int)(fy + 0.5f);

    // preload all 13 neighbors (both halves) before reducing -> 26 loads in flight
    float v0s[NK_], v1s[NK_];
#pragma unroll
    for (int k = 0; k < NK_; k++) {
        int X = min(max(xx + c_OI[k], 0), W_ - 1);
        int Y = min(max(yy + c_OJ[k], 0), H_ - 1);
        const float* p2 = des2 + ((b * D_ + d0) * H_ + Y) * W_ + X;
        v0s[k] = p2[0];
        v1s[k] = p2[64 * H_ * W_];
    }

    float bestv = -1e30f; int bestk = 0;
#pragma unroll
    for (int k = 0; k < NK_; k++) {
        float p = a0 * v0s[k] + a1 * v1s[k];
        for (int s = 32; s > 0; s >>= 1) p += __shfl_xor(p, s, 64);
        if (p > bestv) { bestv = p; bestk = k; }   // strict > = first occurrence
    }

    if (lane == 0) {
        out_scores[(size_t)n * SC_] = bestv;       // pscores
        bool m = (xx >= 0) && (yy >= 0) && (xx < W_) && (yy < H_);
        out_mask[n] = m ? 1.0f : 0.0f;
        int sx = min(max(xx + c_OI[bestk], 0), W_ - 1);
        int sy = min(max(yy + c_OJ[bestk], 0), H_ - 1);
        float q1 = qlt1[(b * H_ + col) * W_ + row];
        float q2 = qlt2[(b * H_ + sy) * W_ + sx];
        out_qlt[n] = (q1 + q2) * 0.5f;
        xy2x_out[n] = xx;
        xy2y_out[n] = yy;
    }
}

// ---------------- gather distr (det2 samples) -------------------------------------------
__global__ __launch_bounds__(64) void prep2_kernel(const float* __restrict__ des2,
                                                   const int* __restrict__ pos_row2,
                                                   const int* __restrict__ pos_col2,
                                                   float* __restrict__ Bmat) {
    int m = blockIdx.x;
    int lane = threadIdx.x;
    int b = m / NCELL_;
    int row = pos_row2[m], col = pos_col2[m];
    const float* p = des2 + ((b * D_ + lane) * H_ + col) * W_ + row;
    Bmat[m * D_ + lane]      = p[0];
    Bmat[m * D_ + lane + 64] = p[64 * H_ * W_];
}

// ---------------- labels: zeros with 1.0 in column 0 ------------------------------------
__global__ void fill_labels(float4* __restrict__ labels4) {
    const long long N4 = (long long)NS_ * SC_ / 4;   // 3,240,900
    long long i = (long long)blockIdx.x * blockDim.x + threadIdx.x;
    long long stride = (long long)gridDim.x * blockDim.x;
    for (; i < N4; i += stride) {
        long long e = i * 4;
        int r = (int)(e % SC_);
        float4 v = make_float4(0.f, 0.f, 0.f, 0.f);
        if      (r == 0)    v.x = 1.0f;
        else if (r == 3600) v.y = 1.0f;
        else if (r == 3599) v.z = 1.0f;
        else if (r == 3598) v.w = 1.0f;
        labels4[i] = v;
    }
}

// ---------------- dscores GEMM (f32, VALU) + dis2 mask epilogue -------------------------
__global__ __launch_bounds__(256) void gemm_kernel(const float* __restrict__ A,
                                                   const float* __restrict__ Bm,
                                                   const int* __restrict__ xy2x,
                                                   const int* __restrict__ xy2y,
                                                   const int* __restrict__ pos_row2,
                                                   const int* __restrict__ pos_col2,
                                                   float* __restrict__ out_scores) {
    __shared__ float As[KC_][TILE_ + 4];   // stride 68 floats: 16B-aligned rows, mild store conflicts
    __shared__ float Bs[KC_][TILE_ + 4];
    int n0 = blockIdx.y * TILE_;
    int m0 = blockIdx.x * TILE_;
    int t  = threadIdx.x;
    int tr = t >> 4;      // 0..15
    int tc = t & 15;      // 0..15

    float acc[4][4] = {{0.f}};

    for (int k0 = 0; k0 < D_; k0 += KC_) {
#pragma unroll
        for (int i = 0; i < 8; i++) {
            int l = t + i * 256;
            int r = l >> 5;            // 0..63 (tile row)
            int c = l & 31;            // 0..31 (k within chunk) -> coalesced global
            int gn = n0 + r;
            As[c][r] = (gn < NS_) ? A[gn * D_ + k0 + c] : 0.0f;
            int gm = m0 + r;
            Bs[c][r] = (gm < NS_) ? Bm[gm * D_ + k0 + c] : 0.0f;
        }
        __syncthreads();
#pragma unroll
        for (int kk = 0; kk < KC_; kk++) {
            float4 av = *(const float4*)&As[kk][tr * 4];
            float4 bv = *(const float4*)&Bs[kk][tc * 4];
            float a[4] = {av.x, av.y, av.z, av.w};
            float bb[4] = {bv.x, bv.y, bv.z, bv.w};
#pragma unroll
            for (int i = 0; i < 4; i++)
#pragma unroll
                for (int j = 0; j < 4; j++)
                    acc[i][j] += a[i] * bb[j];
        }
        __syncthreads();
    }

    // epilogue: dis2 mask, store to scores[:, 1:]
    int nrow[4], xr[4], yr[4], brr[4];
    int mcol[4], rm[4], cm[4], bmb[4];
#pragma unroll
    for (int i = 0; i < 4; i++) {
        nrow[i] = n0 + tr * 4 + i;
        if (nrow[i] < NS_) {
            xr[i] = xy2x[nrow[i]]; yr[i] = xy2y[nrow[i]]; brr[i] = nrow[i] / NCELL_;
        }
    }
#pragma unroll
    for (int j = 0; j < 4; j++) {
        mcol[j] = m0 + tc * 4 + j;
        if (mcol[j] < NS_) {
            rm[j] = pos_row2[mcol[j]]; cm[j] = pos_col2[mcol[j]]; bmb[j] = mcol[j] / NCELL_;
        }
    }
#pragma unroll
    for (int i = 0; i < 4; i++) {
        if (nrow[i] >= NS_) continue;
#pragma unroll
        for (int j = 0; j < 4; j++) {
            if (mcol[j] >= NS_) continue;
            // dis2 = (rows2 - x)^2 + (cols2 - y)^2 (+4 if batch differs); uses UNCLAMPED xy2
            int dx = rm[j] - xr[i];
            int dy = cm[j] - yr[i];
            int dis2 = dx * dx + dy * dy + (bmb[j] != brr[i] ? 4 : 0);
            float v = (dis2 < 4) ? 0.0f : acc[i][j];
            out_scores[(size_t)nrow[i] * SC_ + 1 + mcol[j]] = v;
        }
    }
}

extern "C" void kernel_launch(void* const* d_in, const int* in_sizes, int n_in,
                              void* d_out, int out_size, void* d_ws, size_t ws_size,
                              hipStream_t stream) {
    const float* des1  = (const float*)d_in[0];
    const float* det1  = (const float*)d_in[1];
    const float* qlt1  = (const float*)d_in[2];
    const float* des2  = (const float*)d_in[3];
    const float* det2  = (const float*)d_in[4];
    const float* qlt2  = (const float*)d_in[5];
    const float* aflow = (const float*)d_in[6];

    float* out = (float*)d_out;
    float* out_scores = out;                                        // (3600, 3601)
    float* out_labels = out + (size_t)NS_ * SC_;                    // (3600, 3601)
    float* out_mask   = out + 2 * (size_t)NS_ * SC_;                // (4, 900)
    float* out_qlt    = out + 2 * (size_t)NS_ * SC_ + NS_;          // (3600, 1)

    char* ws = (char*)d_ws;
    int*   pos_row = (int*)(ws);               // [7200] det1 then det2
    int*   pos_col = (int*)(ws + 28800);       // [7200]
    int*   xy2x    = (int*)(ws + 57600);       // [3600]
    int*   xy2y    = (int*)(ws + 72000);       // [3600]
    float* Amat    = (float*)(ws + 86400);     // [3600*128]
    float* Bmat    = (float*)(ws + 1929600);   // [3600*128]

    hipLaunchKernelGGL(sample_kernel, dim3(2 * NS_), dim3(256), 0, stream,
                       det1, det2, pos_row, pos_col);
    hipLaunchKernelGGL(prep1_kernel, dim3(NS_), dim3(64), 0, stream,
                       des1, des2, qlt1, qlt2, aflow, pos_row, pos_col,
                       xy2x, xy2y, Amat, out_scores, out_mask, out_qlt);
    hipLaunchKernelGGL(prep2_kernel, dim3(NS_), dim3(64), 0, stream,
                       des2, pos_row + NS_, pos_col + NS_, Bmat);
    hipLaunchKernelGGL(fill_labels, dim3(2048), dim3(256), 0, stream,
                       (float4*)out_labels);
    hipLaunchKernelGGL(gemm_kernel, dim3((NS_ + TILE_ - 1) / TILE_, (NS_ + TILE_ - 1) / TILE_),
                       dim3(256), 0, stream,
                       Amat, Bmat, xy2x, xy2y, pos_row + NS_, pos_col + NS_, out_scores);
}